// Round 16
// baseline (291.396 us; speedup 1.0000x reference)
//
#include <hip/hip_runtime.h>
#include <hip/hip_fp16.h>
#include <math.h>

#define NEG_SLOPE 0.2f
#define NBLK 256   // partition blocks; bh layout depends on this

typedef _Float16 half8 __attribute__((ext_vector_type(8)));
typedef _Float16 half4 __attribute__((ext_vector_type(4)));
typedef float f32x4 __attribute__((ext_vector_type(4)));
typedef float f32x2 __attribute__((ext_vector_type(2)));

__device__ __forceinline__ float lrelu(float x){ return x > 0.f ? x : NEG_SLOPE*x; }

// ---------------- prep: Wt[p][256] fp16 = W1[k][pi(p)], pi(p)=(p&15)*8+(p>>4) ----------------
__global__ void k_prepw(const float* __restrict__ W, _Float16* __restrict__ Wt){
  int t = blockIdx.x*blockDim.x + threadIdx.x;   // 32768
  int p = t >> 8, k = t & 255;
  int c = ((p & 15) << 3) | (p >> 4);
  Wt[t] = (_Float16)W[k*128 + c];
}

// ---------------- K1: LDS-free fused GEMM + fp8 pack + attention logits ----------------
// 8 waves (512 thr); wave w computes rows w*16..+15 x all 128 cols. MFMA frags
// loaded DIRECTLY from global: A from x (each row read once, 128B/row/ki
// granule), B from 64KB L2-resident Wt. No LDS, no barriers; TLP hides latency.
__global__ __launch_bounds__(512) void k_gemm1(const float* __restrict__ x,
                                               const _Float16* __restrict__ Wt,
                                               const float* __restrict__ as_w,
                                               const float* __restrict__ ad_w,
                                               unsigned* __restrict__ h1p,
                                               float* __restrict__ a_s,
                                               float* __restrict__ a_d, int N){
  int tid = threadIdx.x;
  int w = tid >> 6, lane = tid & 63;
  int fq = lane >> 4, fr = lane & 15;
  int row0 = blockIdx.x * 128;
  int gra = row0 + w*16 + fr;             // A row this lane streams
  bool valid = gra < N;
  const float* xrow = &x[(size_t)(valid ? gra : 0)*256 + fq*8];
  const _Float16* wb = &Wt[(size_t)fr*256 + fq*8];

  f32x4 acc[8];
  #pragma unroll
  for (int n=0;n<8;n++) acc[n] = (f32x4){0.f,0.f,0.f,0.f};

  #pragma unroll 2
  for (int ki=0; ki<8; ki++){
    float4 a0 = make_float4(0.f,0.f,0.f,0.f);
    float4 a1 = make_float4(0.f,0.f,0.f,0.f);
    if (valid){
      a0 = *(const float4*)&xrow[ki*32];
      a1 = *(const float4*)&xrow[ki*32 + 4];
    }
    half8 af;
    af[0]=(_Float16)a0.x; af[1]=(_Float16)a0.y; af[2]=(_Float16)a0.z; af[3]=(_Float16)a0.w;
    af[4]=(_Float16)a1.x; af[5]=(_Float16)a1.y; af[6]=(_Float16)a1.z; af[7]=(_Float16)a1.w;
    half8 bf[8];
    #pragma unroll
    for (int n=0;n<8;n++) bf[n] = *(const half8*)&wb[(size_t)n*4096 + ki*32];
    #pragma unroll
    for (int n=0;n<8;n++)
      acc[n] = __builtin_amdgcn_mfma_f32_16x16x32_f16(af, bf[n], acc[n], 0, 0, 0);
  }
  // fused epilogue: lane (fq,fr) holds channels fr*8..fr*8+7 of rows w*16+fq*4+j
  int head = fr >> 1;
  const float* wsp = &as_w[head*16 + (fr&1)*8];
  const float* wdp = &ad_w[head*16 + (fr&1)*8];
  #pragma unroll
  for (int j=0;j<4;j++){
    int gr = row0 + w*16 + fq*4 + j;   // same for all fr lanes
    if (gr < N){
      float f[8];
      #pragma unroll
      for (int n=0;n<8;n++) f[n] = acc[n][j];
      int w0 = 0, w1 = 0;
      w0 = __builtin_amdgcn_cvt_pk_fp8_f32(f[0], f[1], w0, false);
      w0 = __builtin_amdgcn_cvt_pk_fp8_f32(f[2], f[3], w0, true);
      w1 = __builtin_amdgcn_cvt_pk_fp8_f32(f[4], f[5], w1, false);
      w1 = __builtin_amdgcn_cvt_pk_fp8_f32(f[6], f[7], w1, true);
      *(uint2*)&h1p[(size_t)gr*32 + fr*2] = make_uint2((unsigned)w0,(unsigned)w1);
      float s=0.f, dd=0.f;
      #pragma unroll
      for (int n=0;n<8;n++){ s = fmaf(f[n], wsp[n], s); dd = fmaf(f[n], wdp[n], dd); }
      s  += __shfl_xor(s, 1);
      dd += __shfl_xor(dd, 1);
      if (!(fr & 1)){ a_s[(size_t)gr*8+head] = s; a_d[(size_t)gr*8+head] = dd; }
    }
  }
}

// ---------------- CSR: per-block bucket histogram ----------------
__global__ __launch_bounds__(256) void k_bh(const int* __restrict__ dst, int* __restrict__ bh,
                                            int E, int EE, int NB){
  __shared__ int h[1024];
  int tid = threadIdx.x, blk = blockIdx.x;
  for (int i=tid;i<1024;i+=256) h[i]=0;
  __syncthreads();
  int chunk = (EE + NBLK - 1)/NBLK;
  int e0 = blk*chunk, e1 = min(e0+chunk, EE);
  for (int e=e0+tid; e<e1; e+=256){
    int d = (e<E)? dst[e] : (e-E);
    atomicAdd(&h[d>>7], 1);
  }
  __syncthreads();
  for (int i=tid;i<NB;i+=256) bh[i*NBLK + blk] = h[i];
}

// ---------------- CSR: per-bucket scan over blocks ----------------
__global__ __launch_bounds__(256) void k_scanA(int* __restrict__ bh, int* __restrict__ btot){
  __shared__ int t[256];
  int b = blockIdx.x, tid = threadIdx.x;
  int v = bh[b*NBLK + tid];
  t[tid] = v;
  __syncthreads();
  for (int off=1; off<256; off<<=1){
    int p = (tid>=off)? t[tid-off] : 0;
    __syncthreads();
    t[tid] += p;
    __syncthreads();
  }
  bh[b*NBLK + tid] = t[tid] - v;
  if (tid==255) btot[b] = t[255];
}

// ---------------- CSR: scan of bucket totals -> bucket bases ----------------
__global__ __launch_bounds__(256) void k_bscan(const int* __restrict__ btot, int* __restrict__ bbase,
                                               int* __restrict__ start_, int NB, int N, int EE){
  __shared__ int t[256];
  int tid = threadIdx.x;
  int i0 = tid*4;
  int a0 = (i0+0<NB)? btot[i0+0] : 0;
  int a1 = (i0+1<NB)? btot[i0+1] : 0;
  int a2 = (i0+2<NB)? btot[i0+2] : 0;
  int a3 = (i0+3<NB)? btot[i0+3] : 0;
  int s = a0+a1+a2+a3;
  t[tid] = s;
  __syncthreads();
  for (int off=1; off<256; off<<=1){
    int p = (tid>=off)? t[tid-off] : 0;
    __syncthreads();
    t[tid] += p;
    __syncthreads();
  }
  int excl = t[tid] - s;
  int e0=excl, e1=e0+a0, e2=e1+a1, e3=e2+a2;
  if (i0+0<NB) bbase[i0+0]=e0;
  if (i0+1<NB) bbase[i0+1]=e1;
  if (i0+2<NB) bbase[i0+2]=e2;
  if (i0+3<NB) bbase[i0+3]=e3;
  if (tid==0){ bbase[NB] = EE; start_[N] = EE; }
}

// ---------------- CSR: stable partition fill (packed u32 pairs) ----------------
__global__ __launch_bounds__(256) void k_bfill(const int* __restrict__ src, const int* __restrict__ dst,
                       const int* __restrict__ bh, const int* __restrict__ bbase,
                       unsigned* __restrict__ pairs, int E, int EE, int NB){
  __shared__ int cur[1024];
  int tid = threadIdx.x, blk = blockIdx.x;
  for (int i=tid;i<NB;i+=256) cur[i] = bbase[i] + bh[i*NBLK + blk];
  __syncthreads();
  int chunk = (EE + NBLK - 1)/NBLK;
  int e0 = blk*chunk, e1 = min(e0+chunk, EE);
  for (int e=e0+tid; e<e1; e+=256){
    int s,d;
    if (e<E){ s=src[e]; d=dst[e]; } else { s=e-E; d=s; }
    int p = atomicAdd(&cur[d>>7], 1);
    pairs[p] = ((unsigned)s << 7) | (unsigned)(d & 127);
  }
}

// ---------------- CSR: per-bucket local sort -> start_[] + csr_src ----------------
__global__ __launch_bounds__(256) void k_pb(const int* __restrict__ bbase, const unsigned* __restrict__ pairs,
                    int* __restrict__ start_, int* __restrict__ csr_src, int N){
  __shared__ int hist[128];
  __shared__ int excl[128];
  int b = blockIdx.x;
  int tid = threadIdx.x;
  int base = bbase[b], cnt = bbase[b+1] - base;
  if (tid<128) hist[tid]=0;
  __syncthreads();
  for (int i=tid;i<cnt;i+=256){
    unsigned p = pairs[base+i];
    atomicAdd(&hist[p & 127], 1);
  }
  __syncthreads();
  if (tid < 128) excl[tid] = hist[tid];
  __syncthreads();
  for (int off=1; off<128; off<<=1){
    int p=0;
    if (tid<128 && tid>=off) p = excl[tid-off];
    __syncthreads();
    if (tid<128) excl[tid] += p;
    __syncthreads();
  }
  if (tid < 128){
    int e = excl[tid] - hist[tid];
    int node = (b<<7) + tid;
    if (node < N) start_[node] = base + e;
    hist[tid] = e;
  }
  __syncthreads();
  for (int i=tid;i<cnt;i+=256){
    unsigned p = pairs[base+i];
    int pos = atomicAdd(&hist[p & 127], 1);
    csr_src[base + pos] = (int)(p >> 7);
  }
}

// ---------------- K4: gather aggregation layer 1 (fp8, 16 lanes/edge) ----------------
__global__ __launch_bounds__(256) void k_agg1(const int* __restrict__ start, const int* __restrict__ csr_src,
                      const float* __restrict__ a_s, const float* __restrict__ a_d,
                      const unsigned* __restrict__ h1p, _Float16* __restrict__ acc1h, int N){
  int wid = (blockIdx.x*blockDim.x + threadIdx.x) >> 6;
  int lane = threadIdx.x & 63;
  if (wid >= N) return;
  int d = wid;
  int grp = lane >> 4;
  int fr  = lane & 15;
  int head = fr >> 1;
  float ad = a_d[(size_t)d*8 + head];
  int beg = start[d], end = start[d+1];
  float a0=0.f,a1=0.f,a2=0.f,a3=0.f,a4=0.f,a5=0.f,a6=0.f,a7=0.f,den=0.f;
  int j = beg + grp;
  for (; j + 4 < end; j += 8){
    int s0 = csr_src[j];
    int s1 = csr_src[j+4];
    float e0 = __expf(lrelu(a_s[(size_t)s0*8 + head] + ad));
    float e1 = __expf(lrelu(a_s[(size_t)s1*8 + head] + ad));
    uint2 u0 = *(const uint2*)&h1p[(size_t)s0*32 + fr*2];
    uint2 u1 = *(const uint2*)&h1p[(size_t)s1*32 + fr*2];
    f32x2 p0 = __builtin_amdgcn_cvt_pk_f32_fp8((int)u0.x, false), p1 = __builtin_amdgcn_cvt_pk_f32_fp8((int)u0.x, true);
    f32x2 p2 = __builtin_amdgcn_cvt_pk_f32_fp8((int)u0.y, false), p3 = __builtin_amdgcn_cvt_pk_f32_fp8((int)u0.y, true);
    f32x2 q0 = __builtin_amdgcn_cvt_pk_f32_fp8((int)u1.x, false), q1 = __builtin_amdgcn_cvt_pk_f32_fp8((int)u1.x, true);
    f32x2 q2 = __builtin_amdgcn_cvt_pk_f32_fp8((int)u1.y, false), q3 = __builtin_amdgcn_cvt_pk_f32_fp8((int)u1.y, true);
    a0 = fmaf(e0, p0.x, a0); a1 = fmaf(e0, p0.y, a1); a2 = fmaf(e0, p1.x, a2); a3 = fmaf(e0, p1.y, a3);
    a4 = fmaf(e0, p2.x, a4); a5 = fmaf(e0, p2.y, a5); a6 = fmaf(e0, p3.x, a6); a7 = fmaf(e0, p3.y, a7);
    a0 = fmaf(e1, q0.x, a0); a1 = fmaf(e1, q0.y, a1); a2 = fmaf(e1, q1.x, a2); a3 = fmaf(e1, q1.y, a3);
    a4 = fmaf(e1, q2.x, a4); a5 = fmaf(e1, q2.y, a5); a6 = fmaf(e1, q3.x, a6); a7 = fmaf(e1, q3.y, a7);
    den += e0 + e1;
  }
  if (j < end){
    int s0 = csr_src[j];
    float e0 = __expf(lrelu(a_s[(size_t)s0*8 + head] + ad));
    uint2 u0 = *(const uint2*)&h1p[(size_t)s0*32 + fr*2];
    f32x2 p0 = __builtin_amdgcn_cvt_pk_f32_fp8((int)u0.x, false), p1 = __builtin_amdgcn_cvt_pk_f32_fp8((int)u0.x, true);
    f32x2 p2 = __builtin_amdgcn_cvt_pk_f32_fp8((int)u0.y, false), p3 = __builtin_amdgcn_cvt_pk_f32_fp8((int)u0.y, true);
    a0 = fmaf(e0, p0.x, a0); a1 = fmaf(e0, p0.y, a1); a2 = fmaf(e0, p1.x, a2); a3 = fmaf(e0, p1.y, a3);
    a4 = fmaf(e0, p2.x, a4); a5 = fmaf(e0, p2.y, a5); a6 = fmaf(e0, p3.x, a6); a7 = fmaf(e0, p3.y, a7);
    den += e0;
  }
  a0 += __shfl_xor(a0,16); a1 += __shfl_xor(a1,16); a2 += __shfl_xor(a2,16); a3 += __shfl_xor(a3,16);
  a4 += __shfl_xor(a4,16); a5 += __shfl_xor(a5,16); a6 += __shfl_xor(a6,16); a7 += __shfl_xor(a7,16);
  den += __shfl_xor(den,16);
  a0 += __shfl_xor(a0,32); a1 += __shfl_xor(a1,32); a2 += __shfl_xor(a2,32); a3 += __shfl_xor(a3,32);
  a4 += __shfl_xor(a4,32); a5 += __shfl_xor(a5,32); a6 += __shfl_xor(a6,32); a7 += __shfl_xor(a7,32);
  den += __shfl_xor(den,32);
  float inv = (den > 0.f) ? 1.f/den : 0.f;
  if (grp == 0){
    half8 o;
    o[0]=(_Float16)(a0*inv); o[1]=(_Float16)(a1*inv); o[2]=(_Float16)(a2*inv); o[3]=(_Float16)(a3*inv);
    o[4]=(_Float16)(a4*inv); o[5]=(_Float16)(a5*inv); o[6]=(_Float16)(a6*inv); o[7]=(_Float16)(a7*inv);
    *(half8*)&acc1h[(size_t)d*128 + fr*8] = o;
  }
}

// ---------------- K5: elu + per-node [128]x[128,32] projection + layer-2 logits ----------------
__global__ __launch_bounds__(256) void k_layer2(const _Float16* __restrict__ acc1h, const float* __restrict__ b1,
                        const float* __restrict__ W2, const float* __restrict__ as2w,
                        const float* __restrict__ ad2w,
                        __half* __restrict__ h2ph, float* __restrict__ a_s2,
                        float* __restrict__ a_d2, int N){
  __shared__ float w2s[128][32];
  __shared__ float hs[8][128];
  int tid = threadIdx.x;
  #pragma unroll
  for (int it=0; it<16; it++){
    int idx = it*256 + tid;
    ((float*)w2s)[idx] = W2[idx];
  }
  int sub = tid>>5, ln = tid&31;
  int n = blockIdx.x*8 + sub;
  if (n < N){
    half4 hv = *(const half4*)&acc1h[(size_t)n*128 + ln*4];
    float4 bb = *(const float4*)&b1[ln*4];
    float v0 = (float)hv[0] + bb.x;
    float v1 = (float)hv[1] + bb.y;
    float v2 = (float)hv[2] + bb.z;
    float v3 = (float)hv[3] + bb.w;
    hs[sub][ln*4+0] = v0 > 0.f ? v0 : (__expf(v0) - 1.f);
    hs[sub][ln*4+1] = v1 > 0.f ? v1 : (__expf(v1) - 1.f);
    hs[sub][ln*4+2] = v2 > 0.f ? v2 : (__expf(v2) - 1.f);
    hs[sub][ln*4+3] = v3 > 0.f ? v3 : (__expf(v3) - 1.f);
  }
  __syncthreads();
  if (n >= N) return;
  float o = 0.f;
  #pragma unroll
  for (int k=0;k<128;k++) o = fmaf(hs[sub][k], w2s[k][ln], o);
  h2ph[(size_t)n*32+ln] = __float2half_rn(o);
  float ps = o*as2w[ln], pd = o*ad2w[ln];
  #pragma unroll
  for (int m=16;m;m>>=1){ ps += __shfl_xor(ps,m); pd += __shfl_xor(pd,m); }
  if (ln==0){ a_s2[n]=ps; a_d2[n]=pd; }
}

// ---------------- K6: gather aggregation layer 2 + bias + log_softmax ----------------
__global__ __launch_bounds__(256) void k_agg2(const int* __restrict__ start, const int* __restrict__ csr_src,
                      const float* __restrict__ a_s2, const float* __restrict__ a_d2,
                      const __half* __restrict__ h2ph, const float* __restrict__ b2,
                      float* __restrict__ out, int N){
  int g = (blockIdx.x*blockDim.x + threadIdx.x) >> 5;
  int ln = threadIdx.x & 31;
  if (g >= N) return;
  int d = g;
  int grp = ln >> 4;
  int l16 = ln & 15;
  float ad = a_d2[d];
  int beg = start[d], end = start[d+1];
  float accx=0.f, accy=0.f, den=0.f;
  int j = beg + grp;
  for (; j + 6 < end; j += 8){
    int s0 = csr_src[j];
    int s1 = csr_src[j+2];
    int s2 = csr_src[j+4];
    int s3 = csr_src[j+6];
    float e0 = __expf(lrelu(a_s2[s0] + ad));
    float e1 = __expf(lrelu(a_s2[s1] + ad));
    float e2 = __expf(lrelu(a_s2[s2] + ad));
    float e3 = __expf(lrelu(a_s2[s3] + ad));
    float2 v0 = __half22float2(*(const __half2*)&h2ph[(size_t)s0*32 + l16*2]);
    float2 v1 = __half22float2(*(const __half2*)&h2ph[(size_t)s1*32 + l16*2]);
    float2 v2 = __half22float2(*(const __half2*)&h2ph[(size_t)s2*32 + l16*2]);
    float2 v3 = __half22float2(*(const __half2*)&h2ph[(size_t)s3*32 + l16*2]);
    accx = fmaf(e0, v0.x, accx); accy = fmaf(e0, v0.y, accy);
    accx = fmaf(e1, v1.x, accx); accy = fmaf(e1, v1.y, accy);
    accx = fmaf(e2, v2.x, accx); accy = fmaf(e2, v2.y, accy);
    accx = fmaf(e3, v3.x, accx); accy = fmaf(e3, v3.y, accy);
    den += (e0 + e1) + (e2 + e3);
  }
  for (; j < end; j += 2){
    int s0 = csr_src[j];
    float e0 = __expf(lrelu(a_s2[s0] + ad));
    float2 v0 = __half22float2(*(const __half2*)&h2ph[(size_t)s0*32 + l16*2]);
    accx = fmaf(e0, v0.x, accx); accy = fmaf(e0, v0.y, accy);
    den += e0;
  }
  accx += __shfl_xor(accx, 16);
  accy += __shfl_xor(accy, 16);
  den  += __shfl_xor(den, 16);
  float2 bb = *(const float2*)&b2[l16*2];
  float vx = accx/den + bb.x;
  float vy = accy/den + bb.y;
  float mx = fmaxf(vx, vy);
  #pragma unroll
  for (int m=8;m;m>>=1) mx = fmaxf(mx, __shfl_xor(mx, m));
  float sm = __expf(vx-mx) + __expf(vy-mx);
  #pragma unroll
  for (int m=8;m;m>>=1) sm += __shfl_xor(sm, m);
  float lg = mx + __logf(sm);
  if (grp == 0){
    float2 o = make_float2(vx - lg, vy - lg);
    *(float2*)&out[(size_t)d*32 + l16*2] = o;
  }
}

extern "C" void kernel_launch(void* const* d_in, const int* in_sizes, int n_in,
                              void* d_out, int out_size, void* d_ws, size_t ws_size,
                              hipStream_t stream){
  const float* x   = (const float*)d_in[0];
  const int*   ei  = (const int*)d_in[1];
  const float* W1  = (const float*)d_in[3];
  const float* as1 = (const float*)d_in[4];
  const float* ad1 = (const float*)d_in[5];
  const float* b1  = (const float*)d_in[6];
  const float* W2  = (const float*)d_in[7];
  const float* as2 = (const float*)d_in[8];
  const float* ad2 = (const float*)d_in[9];
  const float* b2  = (const float*)d_in[10];

  int N  = in_sizes[0] / 256;
  int E  = in_sizes[2];
  int EE = E + N;
  const int* src = ei;
  const int* dst = ei + E;

  int NB = (N + 127) >> 7;   // 128 nodes per bucket

  // ---- workspace layout ----
  int* iw = (int*)d_ws;
  int* bh      = iw;                 iw += 1024*NBLK;
  int* btot    = iw;                 iw += 1024;
  int* bbase   = iw;                 iw += 1028;
  int* start_  = iw;                 iw += ((N+1+3)/4)*4;
  int* csr_src = iw;                 iw += ((EE+3)/4)*4;

  float* w = (float*)iw;
  float* a_s1   = w; w += (size_t)N*8;
  float* a_d1   = w; w += (size_t)N*8;
  float* a_s2   = w; w += (size_t)N;
  float* a_d2   = w; w += (size_t)N;
  _Float16* acc1h = (_Float16*)w; w += (size_t)N*64;   // N*128 halfs
  _Float16* h2ph = (_Float16*)w; w += (size_t)N*16;    // N*32 halfs
  _Float16* Wt   = (_Float16*)w; w += 32768/2;
  unsigned* h1p  = (unsigned*)w; w += (size_t)N*16;    // N*32 u32 (fp8 payload)
  float* out    = (float*)d_out;

  // pairs (u32, EE) overlays acc1h (dead until k_agg1)
  unsigned* pairs = (unsigned*)acc1h;

  hipLaunchKernelGGL(k_prepw, dim3(128), dim3(256), 0, stream, W1, Wt);
  hipLaunchKernelGGL(k_gemm1, dim3((N+127)/128), dim3(512), 0, stream, x, Wt, as1, ad1, h1p, a_s1, a_d1, N);
  // CSR build
  hipLaunchKernelGGL(k_bh,    dim3(NBLK), dim3(256), 0, stream, dst, bh, E, EE, NB);
  hipLaunchKernelGGL(k_scanA, dim3(NB),   dim3(256), 0, stream, bh, btot);
  hipLaunchKernelGGL(k_bscan, dim3(1),    dim3(256), 0, stream, btot, bbase, start_, NB, N, EE);
  hipLaunchKernelGGL(k_bfill, dim3(NBLK), dim3(256), 0, stream, src, dst, bh, bbase, pairs, E, EE, NB);
  hipLaunchKernelGGL(k_pb,    dim3(NB),   dim3(256), 0, stream, bbase, pairs, start_, csr_src, N);
  // layer 1 aggregation
  hipLaunchKernelGGL(k_agg1, dim3((N+3)/4), dim3(256), 0, stream, start_, csr_src, a_s1, a_d1, h1p, acc1h, N);
  // layer 2
  hipLaunchKernelGGL(k_layer2, dim3((N+7)/8), dim3(256), 0, stream, acc1h, b1, W2, as2, ad2, (__half*)h2ph, a_s2, a_d2, N);
  hipLaunchKernelGGL(k_agg2, dim3((N+7)/8), dim3(256), 0, stream, start_, csr_src, a_s2, a_d2, (const __half*)h2ph, b2, out, N);
}

// Round 17
// 245.161 us; speedup vs baseline: 1.1886x; 1.1886x over previous
//
#include <hip/hip_runtime.h>
#include <hip/hip_fp16.h>
#include <math.h>

#define NEG_SLOPE 0.2f
#define NBLK 256   // partition blocks; bh layout depends on this

typedef _Float16 half8 __attribute__((ext_vector_type(8)));
typedef _Float16 half4 __attribute__((ext_vector_type(4)));
typedef float f32x4 __attribute__((ext_vector_type(4)));
typedef float f32x2 __attribute__((ext_vector_type(2)));

__device__ __forceinline__ float lrelu(float x){ return x > 0.f ? x : NEG_SLOPE*x; }

// ---------------- prep: Wt[p][256] fp16 = W1[k][pi(p)], pi(p)=(p&15)*8+(p>>4) ----------------
__global__ void k_prepw(const float* __restrict__ W, _Float16* __restrict__ Wt){
  int t = blockIdx.x*blockDim.x + threadIdx.x;   // 32768
  int p = t >> 8, k = t & 255;
  int c = ((p & 15) << 3) | (p >> 4);
  Wt[t] = (_Float16)W[k*128 + c];
}

#define BSTRIDE 264   // halfs; 16B-aligned rows, staggered banks

// ---------------- K1: fused GEMM + fp8 pack + attention logits ----------------
// 8 waves (512 thr). ALL of B (Wt, 64KB) staged in LDS ONCE (one barrier);
// A streamed directly from global (each row read once). ki-loop has zero
// barriers -> compiler software-pipelines; 16 waves/CU hide A latency.
__global__ __launch_bounds__(512) void k_gemm1(const float* __restrict__ x,
                                               const _Float16* __restrict__ Wt,
                                               const float* __restrict__ as_w,
                                               const float* __restrict__ ad_w,
                                               unsigned* __restrict__ h1p,
                                               float* __restrict__ a_s,
                                               float* __restrict__ a_d, int N){
  __shared__ _Float16 bL[128*BSTRIDE];   // 67.6 KB
  int tid = threadIdx.x;
  int w = tid >> 6, lane = tid & 63;
  int fq = lane >> 4, fr = lane & 15;
  int row0 = blockIdx.x * 128;

  // stage all of B: thread t -> row r=t>>2, 64-half chunk c0=(t&3)*64
  {
    int r = tid >> 2;
    int c0 = (tid & 3) * 64;
    #pragma unroll
    for (int i=0;i<8;i++)
      *(half8*)&bL[r*BSTRIDE + c0 + i*8] = *(const half8*)&Wt[(size_t)r*256 + c0 + i*8];
  }
  __syncthreads();

  int gra = row0 + w*16 + fr;             // A row this lane streams
  bool valid = gra < N;
  const float* xrow = &x[(size_t)(valid ? gra : 0)*256 + fq*8];

  f32x4 acc[8];
  #pragma unroll
  for (int n=0;n<8;n++) acc[n] = (f32x4){0.f,0.f,0.f,0.f};

  #pragma unroll 2
  for (int ki=0; ki<8; ki++){
    float4 a0 = make_float4(0.f,0.f,0.f,0.f);
    float4 a1 = make_float4(0.f,0.f,0.f,0.f);
    if (valid){
      a0 = *(const float4*)&xrow[ki*32];
      a1 = *(const float4*)&xrow[ki*32 + 4];
    }
    half8 af;
    af[0]=(_Float16)a0.x; af[1]=(_Float16)a0.y; af[2]=(_Float16)a0.z; af[3]=(_Float16)a0.w;
    af[4]=(_Float16)a1.x; af[5]=(_Float16)a1.y; af[6]=(_Float16)a1.z; af[7]=(_Float16)a1.w;
    half8 bf[8];
    #pragma unroll
    for (int n=0;n<8;n++) bf[n] = *(half8*)&bL[(n*16 + fr)*BSTRIDE + ki*32 + fq*8];
    #pragma unroll
    for (int n=0;n<8;n++)
      acc[n] = __builtin_amdgcn_mfma_f32_16x16x32_f16(af, bf[n], acc[n], 0, 0, 0);
  }
  // fused epilogue: lane (fq,fr) holds channels fr*8..fr*8+7 of rows w*16+fq*4+j
  int head = fr >> 1;
  const float* wsp = &as_w[head*16 + (fr&1)*8];
  const float* wdp = &ad_w[head*16 + (fr&1)*8];
  #pragma unroll
  for (int j=0;j<4;j++){
    int gr = row0 + w*16 + fq*4 + j;   // same for all fr lanes
    if (gr < N){
      float f[8];
      #pragma unroll
      for (int n=0;n<8;n++) f[n] = acc[n][j];
      int w0 = 0, w1 = 0;
      w0 = __builtin_amdgcn_cvt_pk_fp8_f32(f[0], f[1], w0, false);
      w0 = __builtin_amdgcn_cvt_pk_fp8_f32(f[2], f[3], w0, true);
      w1 = __builtin_amdgcn_cvt_pk_fp8_f32(f[4], f[5], w1, false);
      w1 = __builtin_amdgcn_cvt_pk_fp8_f32(f[6], f[7], w1, true);
      *(uint2*)&h1p[(size_t)gr*32 + fr*2] = make_uint2((unsigned)w0,(unsigned)w1);
      float s=0.f, dd=0.f;
      #pragma unroll
      for (int n=0;n<8;n++){ s = fmaf(f[n], wsp[n], s); dd = fmaf(f[n], wdp[n], dd); }
      s  += __shfl_xor(s, 1);
      dd += __shfl_xor(dd, 1);
      if (!(fr & 1)){ a_s[(size_t)gr*8+head] = s; a_d[(size_t)gr*8+head] = dd; }
    }
  }
}

// ---------------- CSR: per-block bucket histogram ----------------
__global__ __launch_bounds__(256) void k_bh(const int* __restrict__ dst, int* __restrict__ bh,
                                            int E, int EE, int NB){
  __shared__ int h[1024];
  int tid = threadIdx.x, blk = blockIdx.x;
  for (int i=tid;i<1024;i+=256) h[i]=0;
  __syncthreads();
  int chunk = (EE + NBLK - 1)/NBLK;
  int e0 = blk*chunk, e1 = min(e0+chunk, EE);
  for (int e=e0+tid; e<e1; e+=256){
    int d = (e<E)? dst[e] : (e-E);
    atomicAdd(&h[d>>7], 1);
  }
  __syncthreads();
  for (int i=tid;i<NB;i+=256) bh[i*NBLK + blk] = h[i];
}

// ---------------- CSR: per-bucket scan over blocks ----------------
__global__ __launch_bounds__(256) void k_scanA(int* __restrict__ bh, int* __restrict__ btot){
  __shared__ int t[256];
  int b = blockIdx.x, tid = threadIdx.x;
  int v = bh[b*NBLK + tid];
  t[tid] = v;
  __syncthreads();
  for (int off=1; off<256; off<<=1){
    int p = (tid>=off)? t[tid-off] : 0;
    __syncthreads();
    t[tid] += p;
    __syncthreads();
  }
  bh[b*NBLK + tid] = t[tid] - v;
  if (tid==255) btot[b] = t[255];
}

// ---------------- CSR: scan of bucket totals -> bucket bases ----------------
__global__ __launch_bounds__(256) void k_bscan(const int* __restrict__ btot, int* __restrict__ bbase,
                                               int* __restrict__ start_, int NB, int N, int EE){
  __shared__ int t[256];
  int tid = threadIdx.x;
  int i0 = tid*4;
  int a0 = (i0+0<NB)? btot[i0+0] : 0;
  int a1 = (i0+1<NB)? btot[i0+1] : 0;
  int a2 = (i0+2<NB)? btot[i0+2] : 0;
  int a3 = (i0+3<NB)? btot[i0+3] : 0;
  int s = a0+a1+a2+a3;
  t[tid] = s;
  __syncthreads();
  for (int off=1; off<256; off<<=1){
    int p = (tid>=off)? t[tid-off] : 0;
    __syncthreads();
    t[tid] += p;
    __syncthreads();
  }
  int excl = t[tid] - s;
  int e0=excl, e1=e0+a0, e2=e1+a1, e3=e2+a2;
  if (i0+0<NB) bbase[i0+0]=e0;
  if (i0+1<NB) bbase[i0+1]=e1;
  if (i0+2<NB) bbase[i0+2]=e2;
  if (i0+3<NB) bbase[i0+3]=e3;
  if (tid==0){ bbase[NB] = EE; start_[N] = EE; }
}

// ---------------- CSR: stable partition fill (packed u32 pairs) ----------------
__global__ __launch_bounds__(256) void k_bfill(const int* __restrict__ src, const int* __restrict__ dst,
                       const int* __restrict__ bh, const int* __restrict__ bbase,
                       unsigned* __restrict__ pairs, int E, int EE, int NB){
  __shared__ int cur[1024];
  int tid = threadIdx.x, blk = blockIdx.x;
  for (int i=tid;i<NB;i+=256) cur[i] = bbase[i] + bh[i*NBLK + blk];
  __syncthreads();
  int chunk = (EE + NBLK - 1)/NBLK;
  int e0 = blk*chunk, e1 = min(e0+chunk, EE);
  for (int e=e0+tid; e<e1; e+=256){
    int s,d;
    if (e<E){ s=src[e]; d=dst[e]; } else { s=e-E; d=s; }
    int p = atomicAdd(&cur[d>>7], 1);
    pairs[p] = ((unsigned)s << 7) | (unsigned)(d & 127);
  }
}

// ---------------- CSR: per-bucket local sort -> start_[] + csr_src ----------------
__global__ __launch_bounds__(256) void k_pb(const int* __restrict__ bbase, const unsigned* __restrict__ pairs,
                    int* __restrict__ start_, int* __restrict__ csr_src, int N){
  __shared__ int hist[128];
  __shared__ int excl[128];
  int b = blockIdx.x;
  int tid = threadIdx.x;
  int base = bbase[b], cnt = bbase[b+1] - base;
  if (tid<128) hist[tid]=0;
  __syncthreads();
  for (int i=tid;i<cnt;i+=256){
    unsigned p = pairs[base+i];
    atomicAdd(&hist[p & 127], 1);
  }
  __syncthreads();
  if (tid < 128) excl[tid] = hist[tid];
  __syncthreads();
  for (int off=1; off<128; off<<=1){
    int p=0;
    if (tid<128 && tid>=off) p = excl[tid-off];
    __syncthreads();
    if (tid<128) excl[tid] += p;
    __syncthreads();
  }
  if (tid < 128){
    int e = excl[tid] - hist[tid];
    int node = (b<<7) + tid;
    if (node < N) start_[node] = base + e;
    hist[tid] = e;
  }
  __syncthreads();
  for (int i=tid;i<cnt;i+=256){
    unsigned p = pairs[base+i];
    int pos = atomicAdd(&hist[p & 127], 1);
    csr_src[base + pos] = (int)(p >> 7);
  }
}

// ---------------- K4: gather aggregation layer 1 (fp8, 16 lanes/edge) ----------------
__global__ __launch_bounds__(256) void k_agg1(const int* __restrict__ start, const int* __restrict__ csr_src,
                      const float* __restrict__ a_s, const float* __restrict__ a_d,
                      const unsigned* __restrict__ h1p, _Float16* __restrict__ acc1h, int N){
  int wid = (blockIdx.x*blockDim.x + threadIdx.x) >> 6;
  int lane = threadIdx.x & 63;
  if (wid >= N) return;
  int d = wid;
  int grp = lane >> 4;
  int fr  = lane & 15;
  int head = fr >> 1;
  float ad = a_d[(size_t)d*8 + head];
  int beg = start[d], end = start[d+1];
  float a0=0.f,a1=0.f,a2=0.f,a3=0.f,a4=0.f,a5=0.f,a6=0.f,a7=0.f,den=0.f;
  int j = beg + grp;
  for (; j + 4 < end; j += 8){
    int s0 = csr_src[j];
    int s1 = csr_src[j+4];
    float e0 = __expf(lrelu(a_s[(size_t)s0*8 + head] + ad));
    float e1 = __expf(lrelu(a_s[(size_t)s1*8 + head] + ad));
    uint2 u0 = *(const uint2*)&h1p[(size_t)s0*32 + fr*2];
    uint2 u1 = *(const uint2*)&h1p[(size_t)s1*32 + fr*2];
    f32x2 p0 = __builtin_amdgcn_cvt_pk_f32_fp8((int)u0.x, false), p1 = __builtin_amdgcn_cvt_pk_f32_fp8((int)u0.x, true);
    f32x2 p2 = __builtin_amdgcn_cvt_pk_f32_fp8((int)u0.y, false), p3 = __builtin_amdgcn_cvt_pk_f32_fp8((int)u0.y, true);
    f32x2 q0 = __builtin_amdgcn_cvt_pk_f32_fp8((int)u1.x, false), q1 = __builtin_amdgcn_cvt_pk_f32_fp8((int)u1.x, true);
    f32x2 q2 = __builtin_amdgcn_cvt_pk_f32_fp8((int)u1.y, false), q3 = __builtin_amdgcn_cvt_pk_f32_fp8((int)u1.y, true);
    a0 = fmaf(e0, p0.x, a0); a1 = fmaf(e0, p0.y, a1); a2 = fmaf(e0, p1.x, a2); a3 = fmaf(e0, p1.y, a3);
    a4 = fmaf(e0, p2.x, a4); a5 = fmaf(e0, p2.y, a5); a6 = fmaf(e0, p3.x, a6); a7 = fmaf(e0, p3.y, a7);
    a0 = fmaf(e1, q0.x, a0); a1 = fmaf(e1, q0.y, a1); a2 = fmaf(e1, q1.x, a2); a3 = fmaf(e1, q1.y, a3);
    a4 = fmaf(e1, q2.x, a4); a5 = fmaf(e1, q2.y, a5); a6 = fmaf(e1, q3.x, a6); a7 = fmaf(e1, q3.y, a7);
    den += e0 + e1;
  }
  if (j < end){
    int s0 = csr_src[j];
    float e0 = __expf(lrelu(a_s[(size_t)s0*8 + head] + ad));
    uint2 u0 = *(const uint2*)&h1p[(size_t)s0*32 + fr*2];
    f32x2 p0 = __builtin_amdgcn_cvt_pk_f32_fp8((int)u0.x, false), p1 = __builtin_amdgcn_cvt_pk_f32_fp8((int)u0.x, true);
    f32x2 p2 = __builtin_amdgcn_cvt_pk_f32_fp8((int)u0.y, false), p3 = __builtin_amdgcn_cvt_pk_f32_fp8((int)u0.y, true);
    a0 = fmaf(e0, p0.x, a0); a1 = fmaf(e0, p0.y, a1); a2 = fmaf(e0, p1.x, a2); a3 = fmaf(e0, p1.y, a3);
    a4 = fmaf(e0, p2.x, a4); a5 = fmaf(e0, p2.y, a5); a6 = fmaf(e0, p3.x, a6); a7 = fmaf(e0, p3.y, a7);
    den += e0;
  }
  a0 += __shfl_xor(a0,16); a1 += __shfl_xor(a1,16); a2 += __shfl_xor(a2,16); a3 += __shfl_xor(a3,16);
  a4 += __shfl_xor(a4,16); a5 += __shfl_xor(a5,16); a6 += __shfl_xor(a6,16); a7 += __shfl_xor(a7,16);
  den += __shfl_xor(den,16);
  a0 += __shfl_xor(a0,32); a1 += __shfl_xor(a1,32); a2 += __shfl_xor(a2,32); a3 += __shfl_xor(a3,32);
  a4 += __shfl_xor(a4,32); a5 += __shfl_xor(a5,32); a6 += __shfl_xor(a6,32); a7 += __shfl_xor(a7,32);
  den += __shfl_xor(den,32);
  float inv = (den > 0.f) ? 1.f/den : 0.f;
  if (grp == 0){
    half8 o;
    o[0]=(_Float16)(a0*inv); o[1]=(_Float16)(a1*inv); o[2]=(_Float16)(a2*inv); o[3]=(_Float16)(a3*inv);
    o[4]=(_Float16)(a4*inv); o[5]=(_Float16)(a5*inv); o[6]=(_Float16)(a6*inv); o[7]=(_Float16)(a7*inv);
    *(half8*)&acc1h[(size_t)d*128 + fr*8] = o;
  }
}

// ---------------- K5: elu + per-node [128]x[128,32] projection + layer-2 logits ----------------
__global__ __launch_bounds__(256) void k_layer2(const _Float16* __restrict__ acc1h, const float* __restrict__ b1,
                        const float* __restrict__ W2, const float* __restrict__ as2w,
                        const float* __restrict__ ad2w,
                        __half* __restrict__ h2ph, float* __restrict__ a_s2,
                        float* __restrict__ a_d2, int N){
  __shared__ float w2s[128][32];
  __shared__ float hs[8][128];
  int tid = threadIdx.x;
  #pragma unroll
  for (int it=0; it<16; it++){
    int idx = it*256 + tid;
    ((float*)w2s)[idx] = W2[idx];
  }
  int sub = tid>>5, ln = tid&31;
  int n = blockIdx.x*8 + sub;
  if (n < N){
    half4 hv = *(const half4*)&acc1h[(size_t)n*128 + ln*4];
    float4 bb = *(const float4*)&b1[ln*4];
    float v0 = (float)hv[0] + bb.x;
    float v1 = (float)hv[1] + bb.y;
    float v2 = (float)hv[2] + bb.z;
    float v3 = (float)hv[3] + bb.w;
    hs[sub][ln*4+0] = v0 > 0.f ? v0 : (__expf(v0) - 1.f);
    hs[sub][ln*4+1] = v1 > 0.f ? v1 : (__expf(v1) - 1.f);
    hs[sub][ln*4+2] = v2 > 0.f ? v2 : (__expf(v2) - 1.f);
    hs[sub][ln*4+3] = v3 > 0.f ? v3 : (__expf(v3) - 1.f);
  }
  __syncthreads();
  if (n >= N) return;
  float o = 0.f;
  #pragma unroll
  for (int k=0;k<128;k++) o = fmaf(hs[sub][k], w2s[k][ln], o);
  h2ph[(size_t)n*32+ln] = __float2half_rn(o);
  float ps = o*as2w[ln], pd = o*ad2w[ln];
  #pragma unroll
  for (int m=16;m;m>>=1){ ps += __shfl_xor(ps,m); pd += __shfl_xor(pd,m); }
  if (ln==0){ a_s2[n]=ps; a_d2[n]=pd; }
}

// ---------------- K6: gather aggregation layer 2 + bias + log_softmax ----------------
__global__ __launch_bounds__(256) void k_agg2(const int* __restrict__ start, const int* __restrict__ csr_src,
                      const float* __restrict__ a_s2, const float* __restrict__ a_d2,
                      const __half* __restrict__ h2ph, const float* __restrict__ b2,
                      float* __restrict__ out, int N){
  int g = (blockIdx.x*blockDim.x + threadIdx.x) >> 5;
  int ln = threadIdx.x & 31;
  if (g >= N) return;
  int d = g;
  int grp = ln >> 4;
  int l16 = ln & 15;
  float ad = a_d2[d];
  int beg = start[d], end = start[d+1];
  float accx=0.f, accy=0.f, den=0.f;
  int j = beg + grp;
  for (; j + 6 < end; j += 8){
    int s0 = csr_src[j];
    int s1 = csr_src[j+2];
    int s2 = csr_src[j+4];
    int s3 = csr_src[j+6];
    float e0 = __expf(lrelu(a_s2[s0] + ad));
    float e1 = __expf(lrelu(a_s2[s1] + ad));
    float e2 = __expf(lrelu(a_s2[s2] + ad));
    float e3 = __expf(lrelu(a_s2[s3] + ad));
    float2 v0 = __half22float2(*(const __half2*)&h2ph[(size_t)s0*32 + l16*2]);
    float2 v1 = __half22float2(*(const __half2*)&h2ph[(size_t)s1*32 + l16*2]);
    float2 v2 = __half22float2(*(const __half2*)&h2ph[(size_t)s2*32 + l16*2]);
    float2 v3 = __half22float2(*(const __half2*)&h2ph[(size_t)s3*32 + l16*2]);
    accx = fmaf(e0, v0.x, accx); accy = fmaf(e0, v0.y, accy);
    accx = fmaf(e1, v1.x, accx); accy = fmaf(e1, v1.y, accy);
    accx = fmaf(e2, v2.x, accx); accy = fmaf(e2, v2.y, accy);
    accx = fmaf(e3, v3.x, accx); accy = fmaf(e3, v3.y, accy);
    den += (e0 + e1) + (e2 + e3);
  }
  for (; j < end; j += 2){
    int s0 = csr_src[j];
    float e0 = __expf(lrelu(a_s2[s0] + ad));
    float2 v0 = __half22float2(*(const __half2*)&h2ph[(size_t)s0*32 + l16*2]);
    accx = fmaf(e0, v0.x, accx); accy = fmaf(e0, v0.y, accy);
    den += e0;
  }
  accx += __shfl_xor(accx, 16);
  accy += __shfl_xor(accy, 16);
  den  += __shfl_xor(den, 16);
  float2 bb = *(const float2*)&b2[l16*2];
  float vx = accx/den + bb.x;
  float vy = accy/den + bb.y;
  float mx = fmaxf(vx, vy);
  #pragma unroll
  for (int m=8;m;m>>=1) mx = fmaxf(mx, __shfl_xor(mx, m));
  float sm = __expf(vx-mx) + __expf(vy-mx);
  #pragma unroll
  for (int m=8;m;m>>=1) sm += __shfl_xor(sm, m);
  float lg = mx + __logf(sm);
  if (grp == 0){
    float2 o = make_float2(vx - lg, vy - lg);
    *(float2*)&out[(size_t)d*32 + l16*2] = o;
  }
}

extern "C" void kernel_launch(void* const* d_in, const int* in_sizes, int n_in,
                              void* d_out, int out_size, void* d_ws, size_t ws_size,
                              hipStream_t stream){
  const float* x   = (const float*)d_in[0];
  const int*   ei  = (const int*)d_in[1];
  const float* W1  = (const float*)d_in[3];
  const float* as1 = (const float*)d_in[4];
  const float* ad1 = (const float*)d_in[5];
  const float* b1  = (const float*)d_in[6];
  const float* W2  = (const float*)d_in[7];
  const float* as2 = (const float*)d_in[8];
  const float* ad2 = (const float*)d_in[9];
  const float* b2  = (const float*)d_in[10];

  int N  = in_sizes[0] / 256;
  int E  = in_sizes[2];
  int EE = E + N;
  const int* src = ei;
  const int* dst = ei + E;

  int NB = (N + 127) >> 7;   // 128 nodes per bucket

  // ---- workspace layout ----
  int* iw = (int*)d_ws;
  int* bh      = iw;                 iw += 1024*NBLK;
  int* btot    = iw;                 iw += 1024;
  int* bbase   = iw;                 iw += 1028;
  int* start_  = iw;                 iw += ((N+1+3)/4)*4;
  int* csr_src = iw;                 iw += ((EE+3)/4)*4;

  float* w = (float*)iw;
  float* a_s1   = w; w += (size_t)N*8;
  float* a_d1   = w; w += (size_t)N*8;
  float* a_s2   = w; w += (size_t)N;
  float* a_d2   = w; w += (size_t)N;
  _Float16* acc1h = (_Float16*)w; w += (size_t)N*64;   // N*128 halfs
  _Float16* h2ph = (_Float16*)w; w += (size_t)N*16;    // N*32 halfs
  _Float16* Wt   = (_Float16*)w; w += 32768/2;
  unsigned* h1p  = (unsigned*)w; w += (size_t)N*16;    // N*32 u32 (fp8 payload)
  float* out    = (float*)d_out;

  // pairs (u32, EE) overlays acc1h (dead until k_agg1)
  unsigned* pairs = (unsigned*)acc1h;

  hipLaunchKernelGGL(k_prepw, dim3(128), dim3(256), 0, stream, W1, Wt);
  hipLaunchKernelGGL(k_gemm1, dim3((N+127)/128), dim3(512), 0, stream, x, Wt, as1, ad1, h1p, a_s1, a_d1, N);
  // CSR build
  hipLaunchKernelGGL(k_bh,    dim3(NBLK), dim3(256), 0, stream, dst, bh, E, EE, NB);
  hipLaunchKernelGGL(k_scanA, dim3(NB),   dim3(256), 0, stream, bh, btot);
  hipLaunchKernelGGL(k_bscan, dim3(1),    dim3(256), 0, stream, btot, bbase, start_, NB, N, EE);
  hipLaunchKernelGGL(k_bfill, dim3(NBLK), dim3(256), 0, stream, src, dst, bh, bbase, pairs, E, EE, NB);
  hipLaunchKernelGGL(k_pb,    dim3(NB),   dim3(256), 0, stream, bbase, pairs, start_, csr_src, N);
  // layer 1 aggregation
  hipLaunchKernelGGL(k_agg1, dim3((N+3)/4), dim3(256), 0, stream, start_, csr_src, a_s1, a_d1, h1p, acc1h, N);
  // layer 2
  hipLaunchKernelGGL(k_layer2, dim3((N+7)/8), dim3(256), 0, stream, acc1h, b1, W2, as2, ad2, (__half*)h2ph, a_s2, a_d2, N);
  hipLaunchKernelGGL(k_agg2, dim3((N+7)/8), dim3(256), 0, stream, start_, csr_src, a_s2, a_d2, (const __half*)h2ph, b2, out, N);
}